// Round 6
// baseline (105.157 us; speedup 1.0000x reference)
//
#include <hip/hip_runtime.h>

#define BN 64
#define TN 1024
#define VN 1024
#define UNITSN 512
#define TWO_PI 6.283185307179586476925286766559f

typedef __attribute__((ext_vector_type(4))) float f32x4;

// K1: s[b*1024+tau] = sum_v x[b, tau, v].
// One wave per TWO rows: 8 nontemporal float4 loads in flight, then one
// 6-step shuffle-reduce pass for both rows (halves serial-chain overhead).
// NT loads: x is a 256MB stream, never reused -> don't allocate in L2.
__global__ void k_reduce_v(const float* __restrict__ x, float* __restrict__ s) {
    int wave = blockIdx.x * 4 + (threadIdx.x >> 6);   // 0..32767
    int lane = threadIdx.x & 63;
    int row0 = wave * 2;
    const f32x4* xr = reinterpret_cast<const f32x4*>(x) + (size_t)row0 * (VN / 4);
    float a0 = 0.f, a1 = 0.f;
#pragma unroll
    for (int i = 0; i < 4; ++i) {
        f32x4 v0 = __builtin_nontemporal_load(&xr[i * 64 + lane]);
        f32x4 v1 = __builtin_nontemporal_load(&xr[256 + i * 64 + lane]);
        a0 += (v0.x + v0.y) + (v0.z + v0.w);
        a1 += (v1.x + v1.y) + (v1.z + v1.w);
    }
#pragma unroll
    for (int off = 32; off > 0; off >>= 1) {
        a0 += __shfl_down(a0, off, 64);
        a1 += __shfl_down(a1, off, 64);
    }
    if (lane == 0) {
        s[row0]     = a0;
        s[row0 + 1] = a1;
    }
}

// K2: F[b*512+t] = sum_tau s[b,tau] * e^{-2*pi*i*tau*t/1024}, t in [0,512)
// One WAVE per (b,t); twiddle from integer phase via hw v_sin/v_cos (full ILP).
__global__ void k_dft(const float* __restrict__ s, float2* __restrict__ F) {
    int w    = (blockIdx.x * blockDim.x + threadIdx.x) >> 6;  // global wave id
    int lane = threadIdx.x & 63;
    int b    = w >> 9;
    int t    = w & 511;
    const float* sb = s + b * TN;

    int p  = (lane * t) & 1023;        // phase index tau*t mod 1024
    int st = (64 * t) & 1023;          // per-step phase increment

    float ar = 0.f, ai = 0.f;
#pragma unroll
    for (int i = 0; i < 16; ++i) {
        float sv  = sb[lane + 64 * i];
        float ang = (float)p * (-TWO_PI / 1024.0f);
        float c   = __cosf(ang);
        float n   = __sinf(ang);
        ar = fmaf(sv, c, ar);
        ai = fmaf(sv, n, ai);
        p  = (p + st) & 1023;
    }
#pragma unroll
    for (int off = 32; off > 0; off >>= 1) {
        ar += __shfl_xor(ar, off, 64);
        ai += __shfl_xor(ai, off, 64);
    }
    if (lane == 0) F[b * UNITSN + t] = make_float2(ar, ai);
}

// K3: W[b,t] = (1/2048) * sum_k (Br[b,k] + i*Bi[b,k]) * F[k,t]
// Wave = 16 t-values x 4 k-segments; shuffle-combine.
__global__ void k_matmul(const float* __restrict__ Br, const float* __restrict__ Bi,
                         const float2* __restrict__ F, float2* __restrict__ W) {
    int tid   = threadIdx.x;
    int lane  = tid & 63;
    int wv    = tid >> 6;
    int b     = blockIdx.x >> 3;
    int tbase = ((blockIdx.x & 7) * 4 + wv) * 16;
    int t     = tbase + (lane & 15);
    int seg   = lane >> 4;
    const float* brp = Br + b * 64 + seg * 16;
    const float* bip = Bi + b * 64 + seg * 16;
    float wr = 0.f, wi = 0.f;
#pragma unroll
    for (int i = 0; i < 16; ++i) {
        float br = brp[i];
        float bi = bip[i];
        float2 f = F[(seg * 16 + i) * UNITSN + t];
        wr = fmaf(br, f.x, wr); wr = fmaf(-bi, f.y, wr);
        wi = fmaf(br, f.y, wi); wi = fmaf(bi, f.x, wi);
    }
    wr += __shfl_xor(wr, 16, 64); wi += __shfl_xor(wi, 16, 64);
    wr += __shfl_xor(wr, 32, 64); wi += __shfl_xor(wi, 32, 64);
    if (seg == 0) {
        const float coef = 1.0f / 2048.0f;
        W[b * UNITSN + t] = make_float2(wr * coef, wi * coef);
    }
}

// K4: out[b][j][t][{re,im}] = W[b,t] + (t+j-511 >= 0 ? W[b, t+j-511] : 0)
// One thread handles 4 consecutive t's: 2 vector W-loads (L2-hit), 4 branchless
// shift loads (clamped addr + cndmask), 2 nontemporal float4 stores (output is
// a 134MB write-once stream -> don't allocate in L2).
__global__ void k_expand(const float2* __restrict__ W, f32x4* __restrict__ out) {
    int idx = blockIdx.x * 256 + threadIdx.x;         // 64*512*128 threads
    int t4 = (idx & 127) * 4;
    int j  = (idx >> 7) & 511;
    int b  = idx >> 16;
    const float2* Wb = W + b * UNITSN;
    const f32x4* W4 = reinterpret_cast<const f32x4*>(Wb);
    f32x4 w01 = W4[t4 >> 1];          // W[t4], W[t4+1]
    f32x4 w23 = W4[(t4 >> 1) + 1];    // W[t4+2], W[t4+3]
    int k0 = t4 + j - 511;
    float2 z0 = Wb[max(k0, 0)];     if (k0 < 0)     z0 = make_float2(0.f, 0.f);
    float2 z1 = Wb[max(k0 + 1, 0)]; if (k0 + 1 < 0) z1 = make_float2(0.f, 0.f);
    float2 z2 = Wb[max(k0 + 2, 0)]; if (k0 + 2 < 0) z2 = make_float2(0.f, 0.f);
    float2 z3 = Wb[max(k0 + 3, 0)]; if (k0 + 3 < 0) z3 = make_float2(0.f, 0.f);
    f32x4 o0 = {w01.x + z0.x, w01.y + z0.y, w01.z + z1.x, w01.w + z1.y};
    f32x4 o1 = {w23.x + z2.x, w23.y + z2.y, w23.z + z3.x, w23.w + z3.y};
    __builtin_nontemporal_store(o0, &out[idx * 2]);
    __builtin_nontemporal_store(o1, &out[idx * 2 + 1]);
}

extern "C" void kernel_launch(void* const* d_in, const int* in_sizes, int n_in,
                              void* d_out, int out_size, void* d_ws, size_t ws_size,
                              hipStream_t stream) {
    const float* x  = (const float*)d_in[0];
    // d_in[1], d_in[2] (A_r, A_i) are provably unused: the shift-register state's
    // column 0 stays zero for all 512 scan steps.
    const float* Br = (const float*)d_in[3];
    const float* Bi = (const float*)d_in[4];

    char* ws = (char*)d_ws;
    float*  s = (float*)ws;                       // 64*1024 f32 = 256 KB
    float2* F = (float2*)(ws + 256 * 1024);       // 64*512 cplx = 256 KB
    float2* W = (float2*)(ws + 512 * 1024);       // 64*512 cplx = 256 KB

    // K1: 65536 rows, 8 rows/block (2 per wave)
    k_reduce_v<<<BN * TN / 8, 256, 0, stream>>>(x, s);
    // K2: 64 b * 512 t waves, 4 waves/block
    k_dft<<<(BN * UNITSN) / 4, 256, 0, stream>>>(s, F);
    // K3: 64 b * 8 t-chunks (wave = 16t x 4seg)
    k_matmul<<<BN * 8, 256, 0, stream>>>(Br, Bi, F, W);
    // K4: 64*512*128 threads, 4 t's each
    k_expand<<<(BN * UNITSN * (UNITSN / 4)) / 256, 256, 0, stream>>>(W, (f32x4*)d_out);
}

// Round 7
// 101.196 us; speedup vs baseline: 1.0391x; 1.0391x over previous
//
#include <hip/hip_runtime.h>

#define BN 64
#define TN 1024
#define VN 1024
#define UNITSN 512
#define TWO_PI 6.283185307179586476925286766559f

// K1: s[b*1024+tau] = sum_v x[b, tau, v].  One wave (64 lanes) per row of 1024
// floats.  (Measured-best shape from R2/R5 — do not modify.)
__global__ void k_reduce_v(const float* __restrict__ x, float* __restrict__ s) {
    int row  = blockIdx.x * 4 + (threadIdx.x >> 6);   // 4 waves per 256-thread block
    int lane = threadIdx.x & 63;
    const float4* xr = reinterpret_cast<const float4*>(x) + (size_t)row * (VN / 4);
    float acc = 0.f;
#pragma unroll
    for (int i = 0; i < 4; ++i) {
        float4 v = xr[i * 64 + lane];                 // consecutive lanes -> consecutive 16B
        acc += (v.x + v.y) + (v.z + v.w);
    }
#pragma unroll
    for (int off = 32; off > 0; off >>= 1)
        acc += __shfl_down(acc, off, 64);
    if (lane == 0) s[row] = acc;
}

// KM: fused middle (K2+K3 of R5, summation order swapped by linearity):
//   g[b,tau] = sum_k (Br[b,k] + i Bi[b,k]) * s[k,tau]        (phase A, -> LDS)
//   W[b,t]   = (1/2048) * sum_tau g[b,tau] * e^{-2pi i tau t/1024}   (phase B)
// Phase B twiddle: DIRECT from integer phase via hw v_sin/v_cos each iteration —
// no loop-carried fp dependence (R3's serial-rotation mistake is the thing this
// fixes).  LDS g reads are 4-distinct-address broadcasts: conflict-free.
__global__ void k_mid(const float* __restrict__ s, const float* __restrict__ Br,
                      const float* __restrict__ Bi, float2* __restrict__ W) {
    __shared__ float2 g[1024];
    __shared__ float2 part[256];

    int b     = blockIdx.x >> 3;
    int tbase = (blockIdx.x & 7) << 6;
    int tid   = threadIdx.x;

    // ---- phase A: g for tau = tid + q*256
    const float* brp = Br + b * 64;
    const float* bip = Bi + b * 64;
    float gr[4] = {0.f, 0.f, 0.f, 0.f};
    float gi[4] = {0.f, 0.f, 0.f, 0.f};
#pragma unroll 8
    for (int k = 0; k < 64; ++k) {
        float br = brp[k];                  // uniform -> scalar
        float bi = bip[k];
        const float* sk = s + k * TN + tid; // coalesced across tid
#pragma unroll
        for (int q = 0; q < 4; ++q) {
            float sv = sk[q * 256];
            gr[q] = fmaf(br, sv, gr[q]);
            gi[q] = fmaf(bi, sv, gi[q]);
        }
    }
#pragma unroll
    for (int q = 0; q < 4; ++q) g[tid + q * 256] = make_float2(gr[q], gi[q]);
    __syncthreads();

    // ---- phase B: thread = (t, tau-residue q0); tau = q0 + 4u
    int t  = tbase + (tid >> 2);
    int q0 = tid & 3;
    int p  = (q0 * t) & 1023;               // phase index tau*t mod 1024
    int st = (4 * t) & 1023;                // increment per u-step

    float ar = 0.f, ai = 0.f;
#pragma unroll 4
    for (int u = 0; u < 256; ++u) {
        float2 gv = g[q0 + 4 * u];
        float ang = (float)p * (-TWO_PI / 1024.0f);
        float c = __cosf(ang);
        float n = __sinf(ang);
        ar = fmaf(gv.x, c, ar); ar = fmaf(-gv.y, n, ar);
        ai = fmaf(gv.x, n, ai); ai = fmaf(gv.y, c, ai);
        p = (p + st) & 1023;                // int update, no fp chain
    }
    part[tid] = make_float2(ar, ai);
    __syncthreads();

    if (tid < 64) {
        float2 a = part[4 * tid],     b2 = part[4 * tid + 1];
        float2 c = part[4 * tid + 2], d  = part[4 * tid + 3];
        const float coef = 1.0f / 2048.0f;
        W[b * UNITSN + tbase + tid] =
            make_float2(((a.x + b2.x) + (c.x + d.x)) * coef,
                        ((a.y + b2.y) + (c.y + d.y)) * coef);
    }
}

// K4: out[b][j][t][{re,im}] = W[b,t] + (t+j-511 >= 0 ? W[b, t+j-511] : 0)
// One thread writes 2 consecutive t's as one float4: lanes write consecutive
// 16B -> perfect coalescing.  (Measured-best shape from R2/R5 — do not modify.)
__global__ void k_expand(const float2* __restrict__ W, float4* __restrict__ out) {
    int idx = blockIdx.x * 256 + threadIdx.x;         // 64*512*256 total
    int t2 = (idx & 255) * 2;
    int j  = (idx >> 8) & 511;
    int b  = idx >> 17;
    const float2* Wb = W + b * UNITSN;
    float4 w01 = *reinterpret_cast<const float4*>(Wb + t2);  // W[t2], W[t2+1]
    int k0 = t2 + j - 511;
    float2 z0 = (k0 >= 0)     ? Wb[k0]     : make_float2(0.f, 0.f);
    float2 z1 = (k0 + 1 >= 0) ? Wb[k0 + 1] : make_float2(0.f, 0.f);
    out[idx] = make_float4(w01.x + z0.x, w01.y + z0.y, w01.z + z1.x, w01.w + z1.y);
}

extern "C" void kernel_launch(void* const* d_in, const int* in_sizes, int n_in,
                              void* d_out, int out_size, void* d_ws, size_t ws_size,
                              hipStream_t stream) {
    const float* x  = (const float*)d_in[0];
    // d_in[1], d_in[2] (A_r, A_i) are provably unused: the shift-register state's
    // column 0 stays zero for all 512 scan steps.
    const float* Br = (const float*)d_in[3];
    const float* Bi = (const float*)d_in[4];

    char* ws = (char*)d_ws;
    float*  s = (float*)ws;                       // 64*1024 f32 = 256 KB
    float2* W = (float2*)(ws + 256 * 1024);       // 64*512 cplx = 256 KB

    // K1: 65536 rows, 4 rows/block
    k_reduce_v<<<BN * TN / 4, 256, 0, stream>>>(x, s);
    // KM: 64 b * 8 t-chunks
    k_mid<<<BN * 8, 256, 0, stream>>>(s, Br, Bi, W);
    // K4: 64*512*256 threads
    k_expand<<<(BN * UNITSN * (UNITSN / 2)) / 256, 256, 0, stream>>>(W, (float4*)d_out);
}

// Round 8
// 100.598 us; speedup vs baseline: 1.0453x; 1.0059x over previous
//
#include <hip/hip_runtime.h>

#define BN 64
#define TN 1024
#define VN 1024
#define UNITSN 512
#define TWO_PI 6.283185307179586476925286766559f

// K1: s[b*1024+tau] = sum_v x[b, tau, v].
// One wave per TWO consecutive rows, PLAIN loads (attribution probe vs R6's
// bundled NT+shape change): 8 float4 loads in flight per wave, one shuffle
// pass for both rows.  Coalescing identical to the 1-row shape (each instr:
// 64 lanes x consecutive 16B).
__global__ void k_reduce_v(const float* __restrict__ x, float* __restrict__ s) {
    int wave = blockIdx.x * 4 + (threadIdx.x >> 6);   // 0..32767
    int lane = threadIdx.x & 63;
    int row0 = wave * 2;
    const float4* xr = reinterpret_cast<const float4*>(x) + (size_t)row0 * (VN / 4);
    float a0 = 0.f, a1 = 0.f;
#pragma unroll
    for (int i = 0; i < 4; ++i) {
        float4 v0 = xr[i * 64 + lane];
        float4 v1 = xr[256 + i * 64 + lane];
        a0 += (v0.x + v0.y) + (v0.z + v0.w);
        a1 += (v1.x + v1.y) + (v1.z + v1.w);
    }
#pragma unroll
    for (int off = 32; off > 0; off >>= 1) {
        a0 += __shfl_down(a0, off, 64);
        a1 += __shfl_down(a1, off, 64);
    }
    if (lane == 0) {
        s[row0]     = a0;
        s[row0 + 1] = a1;
    }
}

// K2: F[b*512+t] = sum_tau s[b,tau] * e^{-2*pi*i*tau*t/1024}, t in [0,512)
// One WAVE per (b,t); twiddle from integer phase via hw v_sin/v_cos (full ILP).
// (R5 exact — measured-best middle.)
__global__ void k_dft(const float* __restrict__ s, float2* __restrict__ F) {
    int w    = (blockIdx.x * blockDim.x + threadIdx.x) >> 6;  // global wave id
    int lane = threadIdx.x & 63;
    int b    = w >> 9;
    int t    = w & 511;
    const float* sb = s + b * TN;

    int p  = (lane * t) & 1023;        // phase index tau*t mod 1024
    int st = (64 * t) & 1023;          // per-step phase increment

    float ar = 0.f, ai = 0.f;
#pragma unroll
    for (int i = 0; i < 16; ++i) {
        float sv  = sb[lane + 64 * i];
        float ang = (float)p * (-TWO_PI / 1024.0f);
        float c   = __cosf(ang);
        float n   = __sinf(ang);
        ar = fmaf(sv, c, ar);
        ai = fmaf(sv, n, ai);
        p  = (p + st) & 1023;
    }
#pragma unroll
    for (int off = 32; off > 0; off >>= 1) {
        ar += __shfl_xor(ar, off, 64);
        ai += __shfl_xor(ai, off, 64);
    }
    if (lane == 0) F[b * UNITSN + t] = make_float2(ar, ai);
}

// K3: W[b,t] = (1/2048) * sum_k (Br[b,k] + i*Bi[b,k]) * F[k,t]
// Wave = 16 t-values x 4 k-segments; shuffle-combine.  (R5 exact.)
__global__ void k_matmul(const float* __restrict__ Br, const float* __restrict__ Bi,
                         const float2* __restrict__ F, float2* __restrict__ W) {
    int tid   = threadIdx.x;
    int lane  = tid & 63;
    int wv    = tid >> 6;
    int b     = blockIdx.x >> 3;
    int tbase = ((blockIdx.x & 7) * 4 + wv) * 16;
    int t     = tbase + (lane & 15);
    int seg   = lane >> 4;
    const float* brp = Br + b * 64 + seg * 16;
    const float* bip = Bi + b * 64 + seg * 16;
    float wr = 0.f, wi = 0.f;
#pragma unroll
    for (int i = 0; i < 16; ++i) {
        float br = brp[i];
        float bi = bip[i];
        float2 f = F[(seg * 16 + i) * UNITSN + t];
        wr = fmaf(br, f.x, wr); wr = fmaf(-bi, f.y, wr);
        wi = fmaf(br, f.y, wi); wi = fmaf(bi, f.x, wi);
    }
    wr += __shfl_xor(wr, 16, 64); wi += __shfl_xor(wi, 16, 64);
    wr += __shfl_xor(wr, 32, 64); wi += __shfl_xor(wi, 32, 64);
    if (seg == 0) {
        const float coef = 1.0f / 2048.0f;
        W[b * UNITSN + t] = make_float2(wr * coef, wi * coef);
    }
}

// K4: out[b][j][t][{re,im}] = W[b,t] + (t+j-511 >= 0 ? W[b, t+j-511] : 0)
// One thread writes 2 consecutive t's as one float4: lanes write consecutive
// 16B -> perfect per-instruction coalescing.  (R2/R5 measured-best — locked.)
__global__ void k_expand(const float2* __restrict__ W, float4* __restrict__ out) {
    int idx = blockIdx.x * 256 + threadIdx.x;         // 64*512*256 total
    int t2 = (idx & 255) * 2;
    int j  = (idx >> 8) & 511;
    int b  = idx >> 17;
    const float2* Wb = W + b * UNITSN;
    float4 w01 = *reinterpret_cast<const float4*>(Wb + t2);  // W[t2], W[t2+1]
    int k0 = t2 + j - 511;
    float2 z0 = (k0 >= 0)     ? Wb[k0]     : make_float2(0.f, 0.f);
    float2 z1 = (k0 + 1 >= 0) ? Wb[k0 + 1] : make_float2(0.f, 0.f);
    out[idx] = make_float4(w01.x + z0.x, w01.y + z0.y, w01.z + z1.x, w01.w + z1.y);
}

extern "C" void kernel_launch(void* const* d_in, const int* in_sizes, int n_in,
                              void* d_out, int out_size, void* d_ws, size_t ws_size,
                              hipStream_t stream) {
    const float* x  = (const float*)d_in[0];
    // d_in[1], d_in[2] (A_r, A_i) are provably unused: the shift-register state's
    // column 0 stays zero for all 512 scan steps.
    const float* Br = (const float*)d_in[3];
    const float* Bi = (const float*)d_in[4];

    char* ws = (char*)d_ws;
    float*  s = (float*)ws;                       // 64*1024 f32 = 256 KB
    float2* F = (float2*)(ws + 256 * 1024);       // 64*512 cplx = 256 KB
    float2* W = (float2*)(ws + 512 * 1024);       // 64*512 cplx = 256 KB

    // K1: 65536 rows, 8 rows/block (2 per wave)
    k_reduce_v<<<BN * TN / 8, 256, 0, stream>>>(x, s);
    // K2: 64 b * 512 t waves, 4 waves/block
    k_dft<<<(BN * UNITSN) / 4, 256, 0, stream>>>(s, F);
    // K3: 64 b * 8 t-chunks (wave = 16t x 4seg)
    k_matmul<<<BN * 8, 256, 0, stream>>>(Br, Bi, F, W);
    // K4: 64*512*256 threads
    k_expand<<<(BN * UNITSN * (UNITSN / 2)) / 256, 256, 0, stream>>>(W, (float4*)d_out);
}